// Round 2
// baseline (70.012 us; speedup 1.0000x reference)
//
#include <hip/hip_runtime.h>
#include <math.h>

// Problem constants
constexpr int Bn = 512;
constexpr int Tn = 512;
constexpr int Dn = 128;
constexpr int Hn = 128;
constexpr int NT = 512;               // threads per block
constexpr int NW = NT / 64;           // waves per block = 8
constexpr int TC = 128;               // rows (timesteps) per chunk
constexpr int NCH = Tn / TC;          // 4 chunks
constexpr int LPT = TC * (Dn / 4) / NT; // float4 loads per thread per chunk = 8

__global__ __launch_bounds__(NT, 4)   // cap VGPR<=128 -> 2 blocks/CU
void single_attn_1pass(const float* __restrict__ input,   // [B,T,D]
                       const int*   __restrict__ mask,    // [B,T]
                       const float* __restrict__ Wt,      // [D,H]
                       const float* __restrict__ Wx,      // [D,H]
                       const float* __restrict__ rate,    // [1]
                       float* __restrict__ out_v,         // [B,D]
                       float* __restrict__ out_a)         // [B,T]
{
    const int b    = blockIdx.x;
    const int tid  = threadIdx.x;
    const int lane = tid & 63;
    const int wid  = tid >> 6;
    const float* __restrict__ inb = input + (size_t)b * Tn * Dn;
    const float4* __restrict__ in4 = (const float4*)inb;

    __shared__ float xs[TC][Dn];      // 64 KiB chunk tile (also aliased for vred at end)
    __shared__ float es[Tn];          // e scores for all t
    __shared__ float ps[TC];          // chunk exp-weights
    __shared__ float dots[TC];        // chunk dot products
    __shared__ int   msk[Tn];
    __shared__ float lv[Dn];
    __shared__ float qs[Hn];
    __shared__ float us[Dn];
    __shared__ float redmax[NW];
    __shared__ float redsum[NW];
    __shared__ int   ired[NW];

    // ---- prefetch chunk 0 into registers (overlaps whole prologue) ----
    float4 x[LPT], y[LPT];
    #pragma unroll
    for (int j = 0; j < LPT; ++j) x[j] = in4[tid + j * NT];

    // ---- mask staging + last_idx ----
    const int mv = mask[b * Tn + tid];
    msk[tid] = mv;
    {
        int ms = mv;
        #pragma unroll
        for (int off = 32; off > 0; off >>= 1) ms += __shfl_down(ms, off, 64);
        if (lane == 0) ired[wid] = ms;
    }
    __syncthreads();
    int last_idx;
    {
        int s = 0;
        #pragma unroll
        for (int w = 0; w < NW; ++w) s += ired[w];
        last_idx = s - 1;
    }

    // ---- lv = input[b,last_idx,:]; q = lv@Wt; u = Wx@q ----
    if (tid < Dn) lv[tid] = inb[(size_t)last_idx * Dn + tid];
    __syncthreads();
    if (tid < Hn) {
        float a0 = 0.f, a1 = 0.f;
        #pragma unroll 16
        for (int d0 = 0; d0 < Dn; d0 += 2) {
            a0 = fmaf(lv[d0],     Wt[d0 * Hn + tid],       a0);
            a1 = fmaf(lv[d0 + 1], Wt[(d0 + 1) * Hn + tid], a1);
        }
        qs[tid] = a0 + a1;
    }
    __syncthreads();
    if (tid < Dn) {
        float a0 = 0.f, a1 = 0.f;
        const float* wxr = Wx + tid * Hn;
        #pragma unroll 16
        for (int h = 0; h < Hn; h += 2) {
            a0 = fmaf(wxr[h],     qs[h],     a0);
            a1 = fmaf(wxr[h + 1], qs[h + 1], a1);
        }
        us[tid] = a0 + a1;
    }
    __syncthreads();

    const float srate = 1.f / (1.f + expf(-rate[0]));
    const float4 u4 = ((const float4*)us)[tid & 31];

    // v-accumulator: group G = tid>>5 owns chunk rows G*8..G*8+7, cols d4 = tid&31 (float4)
    const int G  = tid >> 5;
    const int d4 = tid & 31;
    float4 vacc = make_float4(0.f, 0.f, 0.f, 0.f);
    float m_run = -INFINITY, l_run = 0.f;

    #pragma unroll
    for (int c = 0; c < NCH; ++c) {
        // prefetch next chunk
        if (c + 1 < NCH) {
            #pragma unroll
            for (int j = 0; j < LPT; ++j)
                y[j] = in4[(c + 1) * (TC * Dn / 4) + tid + j * NT];
        }

        // dot partials: thread's float4 j belongs to chunk row (tid>>5)+16*j, col4 (tid&31)
        #pragma unroll
        for (int j = 0; j < LPT; ++j) {
            float p = x[j].x * u4.x + x[j].y * u4.y + x[j].z * u4.z + x[j].w * u4.w;
            #pragma unroll
            for (int m = 1; m < 32; m <<= 1) p += __shfl_xor(p, m, 64);
            if ((tid & 31) == 0) dots[(tid >> 5) + 16 * j] = p;
        }
        __syncthreads();   // Sa: dots visible; prev accumulation done before xs overwrite below

        // scores for this chunk (threads 0..127), then chunk max
        float e = -INFINITY;
        if (tid < TC) {
            const int   tg    = c * TC + tid;
            const float dt    = dots[tid];
            const float sig   = 1.f / (1.f + expf(-dt));
            const float decay = (float)(Tn - tg);             // b_time_decays
            const float den   = srate * (logf(2.72f + (1.f - sig)) * decay);
            e = fmaxf(sig / den, 0.f);
            if (msk[tg] == 0) e = -1e9f;
            es[tg] = e;
        }
        float wm = e;
        #pragma unroll
        for (int off = 32; off > 0; off >>= 1) wm = fmaxf(wm, __shfl_down(wm, off, 64));
        if (lane == 0) redmax[wid] = wm;
        __syncthreads();   // Sb
        float cmax = redmax[0];
        #pragma unroll
        for (int w = 1; w < NW; ++w) cmax = fmaxf(cmax, redmax[w]);
        const float m_new = fmaxf(m_run, cmax);
        const float scale = expf(m_run - m_new);  // 0 on first chunk (m_run=-inf, m_new finite)

        float p = 0.f;
        if (tid < TC) { p = expf(e - m_new); ps[tid] = p; }
        float wsum = p;
        #pragma unroll
        for (int off = 32; off > 0; off >>= 1) wsum += __shfl_down(wsum, off, 64);
        if (lane == 0) redsum[wid] = wsum;

        // stage registers -> LDS while the sum reduction propagates
        #pragma unroll
        for (int j = 0; j < LPT; ++j) ((float4*)xs)[tid + j * NT] = x[j];
        __syncthreads();   // Sd
        float csum = redsum[0];
        #pragma unroll
        for (int w = 1; w < NW; ++w) csum += redsum[w];
        l_run = l_run * scale + csum;
        m_run = m_new;
        vacc.x *= scale; vacc.y *= scale; vacc.z *= scale; vacc.w *= scale;

        // accumulate v from LDS: 8 rows per group, float4 reads (conflict-free)
        #pragma unroll
        for (int r = 0; r < TC / 16; ++r) {
            const int   tl = G * (TC / 16) + r;
            const float pt = ps[tl];
            const float4 xv = ((const float4*)xs)[tl * (Dn / 4) + d4];
            vacc.x = fmaf(pt, xv.x, vacc.x);
            vacc.y = fmaf(pt, xv.y, vacc.y);
            vacc.z = fmaf(pt, xv.z, vacc.z);
            vacc.w = fmaf(pt, xv.w, vacc.w);
        }
        #pragma unroll
        for (int j = 0; j < LPT; ++j) x[j] = y[j];
        __syncthreads();   // Se: accumulation reads complete before next chunk's xs writes
    }

    // ---- outputs ----
    const float inv_l = 1.f / l_run;
    out_a[(size_t)b * Tn + tid] = expf(es[tid] - m_run) * inv_l;

    // reduce vacc across 16 groups; alias vred over xs (all xs reads are done)
    float4* vred = (float4*)xs;   // [16][32] float4 = 8 KiB
    vred[G * 32 + d4] = vacc;
    __syncthreads();
    if (tid < 32) {
        float4 s = vred[tid];
        #pragma unroll
        for (int g2 = 1; g2 < 16; ++g2) {
            float4 t2 = vred[g2 * 32 + tid];
            s.x += t2.x; s.y += t2.y; s.z += t2.z; s.w += t2.w;
        }
        s.x *= inv_l; s.y *= inv_l; s.z *= inv_l; s.w *= inv_l;
        ((float4*)(out_v + (size_t)b * Dn))[tid] = s;
    }
}

extern "C" void kernel_launch(void* const* d_in, const int* in_sizes, int n_in,
                              void* d_out, int out_size, void* d_ws, size_t ws_size,
                              hipStream_t stream) {
    const float* input = (const float*)d_in[0];   // [B,T,D]
    const int*   mask  = (const int*)d_in[1];     // [B,T]
    const float* Wt    = (const float*)d_in[2];   // [D,H]
    const float* Wx    = (const float*)d_in[3];   // [D,H]
    const float* rate  = (const float*)d_in[4];   // [1]

    float* out   = (float*)d_out;
    float* out_v = out;                 // [B,D]  (return order: v, a)
    float* out_a = out + Bn * Dn;       // [B,T]

    single_attn_1pass<<<Bn, NT, 0, stream>>>(input, mask, Wt, Wx, rate, out_v, out_a);
}

// Round 3
// 61.051 us; speedup vs baseline: 1.1468x; 1.1468x over previous
//
#include <hip/hip_runtime.h>
#include <math.h>

// Problem constants
constexpr int Bn = 512;
constexpr int Tn = 512;
constexpr int Dn = 128;
constexpr int Hn = 128;
constexpr int NT = 512;                  // threads per block
constexpr int NW = NT / 64;              // 8 waves
constexpr int HALF = Tn / 2;             // 256 rows in LDS half / 256 in regs
constexpr int JH = HALF * (Dn / 4) / NT; // 16 float4 loads per thread per half

__global__ __launch_bounds__(NT)
void single_attn_fused(const float* __restrict__ input,   // [B,T,D]
                       const int*   __restrict__ mask,    // [B,T]
                       const float* __restrict__ Wt,      // [D,H]
                       const float* __restrict__ Wx,      // [D,H]
                       const float* __restrict__ rate,    // [1]
                       float* __restrict__ out_v,         // [B,D]
                       float* __restrict__ out_a)         // [B,T]
{
    const int b    = blockIdx.x;
    const int tid  = threadIdx.x;
    const int lane = tid & 63;
    const int wid  = tid >> 6;
    const int g32  = tid >> 5;    // 32-lane group id, 0..15
    const int c4   = tid & 31;    // float4 column 0..31
    const float* __restrict__ inb = input + (size_t)b * Tn * Dn;
    const float4* __restrict__ in4 = (const float4*)inb;

    __shared__ float4 xs4[HALF * Dn / 4];   // 128 KiB: rows 0..255
    __shared__ float  dots[Tn];
    __shared__ float  ps[Tn];
    __shared__ float  lv[Dn];
    __shared__ float  qs[Hn];
    __shared__ float  us[Dn];
    __shared__ float  redm[NW];
    __shared__ float  reds[NW];
    __shared__ int    ired[NW];
    __shared__ float4 vp[16][32];           // 8 KiB group partials

    // ---- issue ALL input loads upfront (fully coalesced, 32 in flight) ----
    float4 xa[JH], xb[JH];
    #pragma unroll
    for (int j = 0; j < JH; ++j) xa[j] = in4[tid + j * NT];
    #pragma unroll
    for (int j = 0; j < JH; ++j) xb[j] = in4[HALF * (Dn / 4) + tid + j * NT];

    // ---- prologue: last_idx, lv, q = lv@Wt, u = Wx@q ----
    const int mv = mask[b * Tn + tid];
    {
        int ms = mv;
        #pragma unroll
        for (int off = 32; off > 0; off >>= 1) ms += __shfl_down(ms, off, 64);
        if (lane == 0) ired[wid] = ms;
    }
    __syncthreads();
    int last_idx;
    {
        int s = 0;
        #pragma unroll
        for (int w = 0; w < NW; ++w) s += ired[w];
        last_idx = s - 1;
    }
    if (tid < Dn) lv[tid] = inb[(size_t)last_idx * Dn + tid];
    __syncthreads();
    if (tid < Hn) {
        float a0 = 0.f, a1 = 0.f;
        #pragma unroll 16
        for (int d0 = 0; d0 < Dn; d0 += 2) {
            a0 = fmaf(lv[d0],     Wt[d0 * Hn + tid],       a0);
            a1 = fmaf(lv[d0 + 1], Wt[(d0 + 1) * Hn + tid], a1);
        }
        qs[tid] = a0 + a1;
    }
    __syncthreads();
    if (tid < Dn) {
        float a0 = 0.f, a1 = 0.f;
        const float* wxr = Wx + tid * Hn;
        #pragma unroll 16
        for (int h = 0; h < Hn; h += 2) {
            a0 = fmaf(wxr[h],     qs[h],     a0);
            a1 = fmaf(wxr[h + 1], qs[h + 1], a1);
        }
        us[tid] = a0 + a1;
    }
    __syncthreads();

    const float srate = 1.f / (1.f + expf(-rate[0]));
    const float4 u4 = ((const float4*)us)[c4];

    // ---- dots for LDS half (rows 0..255): consume xa, stage to LDS ----
    #pragma unroll
    for (int j = 0; j < JH; ++j) {
        float p = xa[j].x * u4.x + xa[j].y * u4.y + xa[j].z * u4.z + xa[j].w * u4.w;
        #pragma unroll
        for (int m = 1; m < 32; m <<= 1) p += __shfl_xor(p, m, 64);
        if (c4 == 0) dots[g32 + 16 * j] = p;
        xs4[tid + j * NT] = xa[j];
    }
    // ---- dots for register half (rows 256..511): keep xb in regs ----
    #pragma unroll
    for (int j = 0; j < JH; ++j) {
        float p = xb[j].x * u4.x + xb[j].y * u4.y + xb[j].z * u4.z + xb[j].w * u4.w;
        #pragma unroll
        for (int m = 1; m < 32; m <<= 1) p += __shfl_xor(p, m, 64);
        if (c4 == 0) dots[HALF + g32 + 16 * j] = p;
    }
    __syncthreads();   // dots[] + xs4[] visible

    // ---- scores (thread tid handles t = tid) ----
    const float dt    = dots[tid];
    const float sig   = 1.f / (1.f + expf(-dt));
    const float decay = (float)(Tn - tid);          // b_time_decays[t] = T - t
    const float den   = srate * (logf(2.72f + (1.f - sig)) * decay);
    float e = fmaxf(sig / den, 0.f);
    if (mv == 0) e = -1e9f;

    // ---- one softmax round: block max, then block sum ----
    float wm = e;
    #pragma unroll
    for (int off = 32; off > 0; off >>= 1) wm = fmaxf(wm, __shfl_down(wm, off, 64));
    if (lane == 0) redm[wid] = wm;
    __syncthreads();
    float m = redm[0];
    #pragma unroll
    for (int w = 1; w < NW; ++w) m = fmaxf(m, redm[w]);

    const float p = expf(e - m);
    ps[tid] = p;
    float ws = p;
    #pragma unroll
    for (int off = 32; off > 0; off >>= 1) ws += __shfl_down(ws, off, 64);
    if (lane == 0) reds[wid] = ws;
    __syncthreads();   // reds + ps visible
    float l = 0.f;
    #pragma unroll
    for (int w = 0; w < NW; ++w) l += reds[w];
    const float inv_l = 1.f / l;

    out_a[(size_t)b * Tn + tid] = p * inv_l;

    // ---- v accumulation: LDS half + register half ----
    float4 vacc = make_float4(0.f, 0.f, 0.f, 0.f);
    #pragma unroll
    for (int r = 0; r < 16; ++r) {
        const int   row = g32 + 16 * r;             // rows 0..255
        const float pt  = ps[row];                  // broadcast within group
        const float4 xv = xs4[row * 32 + c4];
        vacc.x = fmaf(pt, xv.x, vacc.x);
        vacc.y = fmaf(pt, xv.y, vacc.y);
        vacc.z = fmaf(pt, xv.z, vacc.z);
        vacc.w = fmaf(pt, xv.w, vacc.w);
    }
    #pragma unroll
    for (int j = 0; j < JH; ++j) {
        const int   row = HALF + g32 + 16 * j;      // rows 256..511 (this thread's xb rows)
        const float pt  = ps[row];
        vacc.x = fmaf(pt, xb[j].x, vacc.x);
        vacc.y = fmaf(pt, xb[j].y, vacc.y);
        vacc.z = fmaf(pt, xb[j].z, vacc.z);
        vacc.w = fmaf(pt, xb[j].w, vacc.w);
    }
    vp[g32][c4] = vacc;
    __syncthreads();
    if (tid < 32) {
        float4 s = vp[0][tid];
        #pragma unroll
        for (int g2 = 1; g2 < 16; ++g2) {
            float4 t2 = vp[g2][tid];
            s.x += t2.x; s.y += t2.y; s.z += t2.z; s.w += t2.w;
        }
        s.x *= inv_l; s.y *= inv_l; s.z *= inv_l; s.w *= inv_l;
        ((float4*)(out_v + (size_t)b * Dn))[tid] = s;
    }
}

extern "C" void kernel_launch(void* const* d_in, const int* in_sizes, int n_in,
                              void* d_out, int out_size, void* d_ws, size_t ws_size,
                              hipStream_t stream) {
    const float* input = (const float*)d_in[0];   // [B,T,D]
    const int*   mask  = (const int*)d_in[1];     // [B,T]
    const float* Wt    = (const float*)d_in[2];   // [D,H]
    const float* Wx    = (const float*)d_in[3];   // [D,H]
    const float* rate  = (const float*)d_in[4];   // [1]

    float* out   = (float*)d_out;
    float* out_v = out;                 // [B,D]  (return order: v, a)
    float* out_a = out + Bn * Dn;       // [B,T]

    single_attn_fused<<<Bn, NT, 0, stream>>>(input, mask, Wt, Wx, rate, out_v, out_a);
}

// Round 4
// 50.501 us; speedup vs baseline: 1.3864x; 1.2089x over previous
//
#include <hip/hip_runtime.h>
#include <math.h>

// Problem constants
constexpr int Bn = 512;
constexpr int Tn = 512;
constexpr int Dn = 128;
constexpr int Hn = 128;
constexpr int NT = 512;       // threads per block (one block per batch)
constexpr int NW = NT / 64;   // 8 waves

__global__ __launch_bounds__(NT, 4)   // 4 waves/SIMD -> 2 blocks/CU co-resident (VGPR<=128)
void single_attn_2pass(const float* __restrict__ input,   // [B,T,D]
                       const int*   __restrict__ mask,    // [B,T]
                       const float* __restrict__ Wt,      // [D,H]
                       const float* __restrict__ Wx,      // [D,H]
                       const float* __restrict__ rate,    // [1]
                       float* __restrict__ out_v,         // [B,D]
                       float* __restrict__ out_a)         // [B,T]
{
    const int b    = blockIdx.x;
    const int tid  = threadIdx.x;
    const int lane = tid & 63;
    const int wid  = tid >> 6;
    const float* __restrict__ inb = input + (size_t)b * Tn * Dn;
    const float4* __restrict__ in4 = (const float4*)inb;

    __shared__ float  dots[Tn];     // 2 KB
    __shared__ float  ps[Tn];       // 2 KB
    __shared__ float  lv[Dn];
    __shared__ float  qs[Hn];
    __shared__ float  us[Dn];
    __shared__ float  redm[NW];
    __shared__ float  reds[NW];
    __shared__ int    ired[NW];
    __shared__ float4 vp[16][32];   // 8 KB

    // ---- prologue: last_idx, lv, q = lv@Wt, u = Wx@q ----
    const int mv = mask[b * Tn + tid];
    {
        int ms = mv;
        #pragma unroll
        for (int off = 32; off > 0; off >>= 1) ms += __shfl_down(ms, off, 64);
        if (lane == 0) ired[wid] = ms;
    }
    __syncthreads();
    int last_idx;
    {
        int s = 0;
        #pragma unroll
        for (int w = 0; w < NW; ++w) s += ired[w];
        last_idx = s - 1;
    }
    if (tid < Dn) lv[tid] = inb[(size_t)last_idx * Dn + tid];
    __syncthreads();
    if (tid < Hn) {
        float a0 = 0.f, a1 = 0.f;
        #pragma unroll 16
        for (int d0 = 0; d0 < Dn; d0 += 2) {
            a0 = fmaf(lv[d0],     Wt[d0 * Hn + tid],       a0);
            a1 = fmaf(lv[d0 + 1], Wt[(d0 + 1) * Hn + tid], a1);
        }
        qs[tid] = a0 + a1;
    }
    __syncthreads();
    if (tid < Dn) {
        float a0 = 0.f, a1 = 0.f;
        const float* wxr = Wx + tid * Hn;
        #pragma unroll 16
        for (int h = 0; h < Hn; h += 2) {
            a0 = fmaf(wxr[h],     qs[h],     a0);
            a1 = fmaf(wxr[h + 1], qs[h + 1], a1);
        }
        us[tid] = a0 + a1;
    }
    __syncthreads();

    const float srate = 1.f / (1.f + expf(-rate[0]));

    // ---- phase 1: coalesced dot pass. 16 lanes per row, 2 float4 per lane ----
    {
        const int seg = tid & 15;      // 16 segments of 8 floats
        const int rg  = tid >> 4;      // 32 rows per iteration
        const float4 u40 = ((const float4*)us)[seg * 2];
        const float4 u41 = ((const float4*)us)[seg * 2 + 1];
        #pragma unroll 4
        for (int it = 0; it < Tn / 32; ++it) {
            const int row = it * 32 + rg;
            const float4 x0 = in4[row * 32 + seg * 2];
            const float4 x1 = in4[row * 32 + seg * 2 + 1];
            float p = x0.x * u40.x + x0.y * u40.y + x0.z * u40.z + x0.w * u40.w;
            p = fmaf(x1.x, u41.x, p);
            p = fmaf(x1.y, u41.y, p);
            p = fmaf(x1.z, u41.z, p);
            p = fmaf(x1.w, u41.w, p);
            #pragma unroll
            for (int m = 1; m < 16; m <<= 1) p += __shfl_xor(p, m, 64);
            if (seg == 0) dots[row] = p;
        }
    }
    __syncthreads();

    // ---- scores (thread tid handles t = tid) ----
    const float dt    = dots[tid];
    const float sig   = 1.f / (1.f + expf(-dt));
    const float decay = (float)(Tn - tid);          // b_time_decays[t] = T - t
    const float den   = srate * (logf(2.72f + (1.f - sig)) * decay);
    float e = fmaxf(sig / den, 0.f);
    if (mv == 0) e = -1e9f;

    // ---- softmax: block max then block sum ----
    float wm = e;
    #pragma unroll
    for (int off = 32; off > 0; off >>= 1) wm = fmaxf(wm, __shfl_down(wm, off, 64));
    if (lane == 0) redm[wid] = wm;
    __syncthreads();
    float m = redm[0];
    #pragma unroll
    for (int w = 1; w < NW; ++w) m = fmaxf(m, redm[w]);

    const float p = expf(e - m);
    ps[tid] = p;
    float wsum = p;
    #pragma unroll
    for (int off = 32; off > 0; off >>= 1) wsum += __shfl_down(wsum, off, 64);
    if (lane == 0) reds[wid] = wsum;
    __syncthreads();   // ps + reds visible
    float l = 0.f;
    #pragma unroll
    for (int w = 0; w < NW; ++w) l += reds[w];
    const float inv_l = 1.f / l;

    out_a[(size_t)b * Tn + tid] = p * inv_l;

    // ---- phase 2: v[d] = sum_t a[t]*x[t,d], coalesced re-read (L3-resident) ----
    {
        const int c = tid & 31;          // float4 column
        const int g = tid >> 5;          // group 0..15
        float4 vacc = make_float4(0.f, 0.f, 0.f, 0.f);
        #pragma unroll 4
        for (int k = 0; k < Tn / 16; ++k) {
            const int   tt = k * 16 + g;
            const float pt = ps[tt];
            const float4 xv = in4[(size_t)tt * 32 + c];
            vacc.x = fmaf(pt, xv.x, vacc.x);
            vacc.y = fmaf(pt, xv.y, vacc.y);
            vacc.z = fmaf(pt, xv.z, vacc.z);
            vacc.w = fmaf(pt, xv.w, vacc.w);
        }
        vp[g][c] = vacc;
    }
    __syncthreads();
    if (tid < 32) {
        float4 s = vp[0][tid];
        #pragma unroll
        for (int g2 = 1; g2 < 16; ++g2) {
            float4 t2 = vp[g2][tid];
            s.x += t2.x; s.y += t2.y; s.z += t2.z; s.w += t2.w;
        }
        s.x *= inv_l; s.y *= inv_l; s.z *= inv_l; s.w *= inv_l;
        ((float4*)(out_v + (size_t)b * Dn))[tid] = s;
    }
}

extern "C" void kernel_launch(void* const* d_in, const int* in_sizes, int n_in,
                              void* d_out, int out_size, void* d_ws, size_t ws_size,
                              hipStream_t stream) {
    const float* input = (const float*)d_in[0];   // [B,T,D]
    const int*   mask  = (const int*)d_in[1];     // [B,T]
    const float* Wt    = (const float*)d_in[2];   // [D,H]
    const float* Wx    = (const float*)d_in[3];   // [D,H]
    const float* rate  = (const float*)d_in[4];   // [1]

    float* out   = (float*)d_out;
    float* out_v = out;                 // [B,D]  (return order: v, a)
    float* out_a = out + Bn * Dn;       // [B,T]

    single_attn_2pass<<<Bn, NT, 0, stream>>>(input, mask, Wt, Wx, rate, out_v, out_a);
}